// Round 14
// baseline (709.847 us; speedup 1.0000x reference)
//
#include <hip/hip_runtime.h>
#include <stdint.h>

typedef unsigned short u16;
typedef unsigned int   u32;
typedef __attribute__((ext_vector_type(4))) float f32x4;
typedef __attribute__((ext_vector_type(8))) short bf16x8;

__device__ __forceinline__ u16 f2bf(float f) {
    u32 i = __float_as_uint(f);
    u32 r = (i + 0x7fffu + ((i >> 16) & 1u)) >> 16;   // RNE
    return (u16)r;
}
__device__ __forceinline__ float bf2f(u16 u) {
    return __uint_as_float(((u32)u) << 16);
}
__device__ __forceinline__ u32 cvt2bf(float a, float b) {
    u32 r;
    asm("v_cvt_pk_bf16_f32 %0, %1, %2" : "=v"(r) : "v"(a), "v"(b));
    return r;
}

#define GLOAD16(g, l) __builtin_amdgcn_global_load_lds( \
    (const __attribute__((address_space(1))) void*)(g), \
    (__attribute__((address_space(3))) void*)(l), 16, 0, 0)

#define RAW_BARRIER()  asm volatile("s_barrier" ::: "memory")
#define VMCNT(n)       asm volatile("s_waitcnt vmcnt(" #n ")" ::: "memory")

// ---------------------------------------------------------------- GEMM + fused GCN-self epilogue (R8/R11 best config)
__global__ __launch_bounds__(512, 1)
void k_gemm2g(const u16* __restrict__ A0, const u16* __restrict__ A1,
              const u16* __restrict__ B0, const u16* __restrict__ B1,
              const u16* __restrict__ Gres,
              const float* __restrict__ gb0, const float* __restrict__ gb1,
              u16* __restrict__ Ha, u16* __restrict__ Hb,
              float* __restrict__ XW0a, float* __restrict__ XW0b)
{
    __shared__ alignas(16) u16 LDS[65536];      // 128 KB = 4 tile-buffers x 16384 u16
    const int NT = 128;                          // K / BK = 4096 / 32
    const int tid  = threadIdx.x;
    const int lane = tid & 63;
    const int wid  = tid >> 6;
    const int wr = wid >> 2, wc = wid & 3;       // 2 x 4 wave grid, per-wave C 128x64

    const int bid = blockIdx.x;
    const int swz = (bid & 7) * 32 + (bid >> 3);
    const int z   = swz >> 7;
    const int rem = swz & 127;
    const int bm = (rem >> 4) * 256;             // 8 m-tiles
    const int bn = (rem & 15) * 256;             // 16 n-tiles

    const u16* Ap = (z ? A1 : A0) + (size_t)bm * 4096;
    const u16* Bp = (z ? B1 : B0) + (size_t)bn * 4096;

    int aoff[8], boff[4];
    #pragma unroll
    for (int i = 0; i < 8; ++i) {
        int row = wr * 128 + i * 16 + (lane & 15);
        int sp  = (lane >> 4) ^ ((row >> 1) & 3);
        aoff[i] = row * 32 + sp * 8;
    }
    #pragma unroll
    for (int j = 0; j < 4; ++j) {
        int row = wc * 64 + j * 16 + (lane & 15);
        int sp  = (lane >> 4) ^ ((row >> 1) & 3);
        boff[j] = row * 32 + sp * 8;
    }

    auto stage = [&](int t) {
        if (t >= NT) return;
        const int k0  = t << 5;
        u16* buf = LDS + ((t & 3) << 14);
        #pragma unroll
        for (int h = 0; h < 2; ++h) {
            const int c  = tid + h * 512;
            const int r  = c >> 2;
            const int sl = (c & 3) ^ ((r >> 1) & 3);
            GLOAD16(Ap + (size_t)r * 4096 + k0 + sl * 8, buf + c * 8);
            GLOAD16(Bp + (size_t)r * 4096 + k0 + sl * 8, buf + 8192 + c * 8);
        }
    };

    f32x4 acc[8][4] = {};

    auto compute = [&](int t) {
        const u16* buf = LDS + ((t & 3) << 14);
        bf16x8 af[8], bf[4];
        #pragma unroll
        for (int j = 0; j < 4; ++j) bf[j] = *(const bf16x8*)(buf + 8192 + boff[j]);
        #pragma unroll
        for (int i = 0; i < 8; ++i) af[i] = *(const bf16x8*)(buf + aoff[i]);
        __builtin_amdgcn_s_setprio(1);
        #pragma unroll
        for (int i = 0; i < 8; ++i)
            #pragma unroll
            for (int j = 0; j < 4; ++j)
                acc[i][j] = __builtin_amdgcn_mfma_f32_16x16x32_bf16(af[i], bf[j], acc[i][j], 0, 0, 0);
        __builtin_amdgcn_s_setprio(0);
    };

    stage(0); stage(1); stage(2);
    for (int t = 0; t < NT - 3; ++t) {
        VMCNT(8);
        RAW_BARRIER();
        stage(t + 3);
        compute(t);
    }
    VMCNT(8);  RAW_BARRIER(); compute(NT - 3);
    VMCNT(4);  RAW_BARRIER(); compute(NT - 2);
    VMCNT(0);  RAW_BARRIER(); compute(NT - 1);

    // ---------------- epilogue
    const int orow = (lane >> 4) * 4, ocol = lane & 15;
    const float* gbv = z ? gb1 : gb0;
    u16* H = z ? Hb : Ha;

    #pragma unroll
    for (int j = 0; j < 4; ++j) {
        const int o = bn + wc * 64 + j * 16 + ocol;
        const float gbo = gbv[o];
        #pragma unroll
        for (int i = 0; i < 8; ++i) {
            const int rbase = bm + wr * 128 + i * 16 + orow;
            #pragma unroll
            for (int v = 0; v < 4; ++v) {
                const size_t e = (size_t)(rbase + v) * 4096 + o;
                float g = bf2f(Gres[e]);
                H[e] = f2bf(__fmaf_rn(0.05f, g, acc[i][j][v] + gbo));
            }
        }
    }
    if (bm == 0 && wr == 0) {
        float* XW0 = z ? XW0b : XW0a;
        #pragma unroll
        for (int i = 0; i < 8; ++i) {
            #pragma unroll
            for (int j = 0; j < 4; ++j) {
                float* cp = XW0 + (size_t)(i * 16 + orow) * 4096 + (bn + wc * 64 + j * 16 + ocol);
                #pragma unroll
                for (int v = 0; v < 4; ++v)
                    cp[(size_t)v * 4096] = acc[i][j][v];
            }
        }
    }
}

// ---------------------------------------------------------------- device helpers
__device__ __forceinline__ void wcvt_body(int wb, const float* __restrict__ W0,
                                          const float* __restrict__ W1,
                                          u16* __restrict__ Wb0, u16* __restrict__ Wb1)
{
    int half = wb >> 13;
    const float* W = half ? W1 : W0;
    u16* Wb = half ? Wb1 : Wb0;
    size_t e = ((size_t)(wb & 8191) * 256 + threadIdx.x) * 8;
    f32x4 a = *(const f32x4*)(W + e);
    f32x4 b = *(const f32x4*)(W + e + 4);
    uint4 r;
    r.x = cvt2bf(a[0], a[1]); r.y = cvt2bf(a[2], a[3]);
    r.z = cvt2bf(b[0], b[1]); r.w = cvt2bf(b[2], b[3]);
    *(uint4*)(Wb + e) = r;
}

__device__ __forceinline__ void prep_body(const float* __restrict__ A, float* dd)
{
    int r = threadIdx.x;
    if (r >= 128) return;
    int cc = 0, cr = 0;
    for (int j = 0; j < 128; ++j) {
        if (j == r) continue;
        if (A[(j << 7) + r] != 0.f) cc++;
        if (A[(r << 7) + j] != 0.f) cr++;
    }
    float d1 = 1.f + (float)cc, d2 = 1.f + (float)cr;
    dd[r]       = rsqrtf(d1); dd[128 + r] = 1.f / d1;   // dis1, inv1
    dd[256 + r] = rsqrtf(d2); dd[384 + r] = 1.f / d2;   // dis2, inv2
}

__device__ __forceinline__ void gcnfix_body(int fb, const float* __restrict__ XW0a,
              const float* __restrict__ XW0b,
              const u16* __restrict__ G, const float* __restrict__ Af,
              const float* __restrict__ dd,
              const float* __restrict__ gb0, const float* __restrict__ gb1,
              u16* __restrict__ Ha, u16* __restrict__ Hb)
{
    const int prob = fb >> 9;          // 0: mp1 (A), 1: mp2 (A^T)
    const int rem  = fb & 511;
    const int t4 = rem * 256 + threadIdx.x;
    const int r = t4 >> 10, og = (t4 & 1023) << 2;
    const float* XW0 = prob ? XW0b : XW0a;
    const float* dis = prob ? dd + 256 : dd;
    const float* inv = prob ? dd + 384 : dd + 128;
    const float* gb  = prob ? gb1  : gb0;
    u16* H = prob ? Hb : Ha;

    const size_t e = ((size_t)r << 12) + og;
    f32x4 xw = *(const f32x4*)(XW0 + e);
    f32x4 s = {0.f, 0.f, 0.f, 0.f};
    for (int j = 0; j < 128; ++j) {
        float av = prob ? Af[(r << 7) + j] : Af[(j << 7) + r];
        float wv = ((av != 0.f) && (j != r)) ? dis[j] : 0.f;
        f32x4 xv = *(const f32x4*)(XW0 + ((size_t)j << 12) + og);
        #pragma unroll
        for (int q = 0; q < 4; ++q) s[q] = __fmaf_rn(wv, xv[q], s[q]);
    }
    const float iv = inv[r], dr = dis[r];
    f32x4 gb4 = *(const f32x4*)(gb + og);
    uint2 gv = *(const uint2*)(G + e);
    float g0 = __uint_as_float(gv.x << 16), g1 = __uint_as_float(gv.x & 0xffff0000u);
    float g2 = __uint_as_float(gv.y << 16), g3 = __uint_as_float(gv.y & 0xffff0000u);
    float y0 = __fmaf_rn(0.05f, g0, __fmaf_rn(dr, s[0], xw[0] * iv) + gb4[0]);
    float y1 = __fmaf_rn(0.05f, g1, __fmaf_rn(dr, s[1], xw[1] * iv) + gb4[1]);
    float y2 = __fmaf_rn(0.05f, g2, __fmaf_rn(dr, s[2], xw[2] * iv) + gb4[2]);
    float y3 = __fmaf_rn(0.05f, g3, __fmaf_rn(dr, s[3], xw[3] * iv) + gb4[3]);
    uint2 rr;
    rr.x = cvt2bf(y0, y1);
    rr.y = cvt2bf(y2, y3);
    *(uint2*)(H + e) = rr;
}

// ---------------------------------------------------------------- wcvt hop1 + prep (no LDS, full occupancy)
__global__ __launch_bounds__(256)
void k_wcvtprep(const float* __restrict__ W0, const float* __restrict__ W1,
                u16* __restrict__ Wb0, u16* __restrict__ Wb1,
                const float* __restrict__ A, float* __restrict__ dd)
{
    const int bid = blockIdx.x;
    if (bid < 16384) wcvt_body(bid, W0, W1, Wb0, Wb1);
    else             prep_body(A, dd);
}

// ---------------------------------------------------------------- mega2: gcnfix hop1 | wcvt hop2 (no LDS)
__global__ __launch_bounds__(256)
void k_mega2(const float* __restrict__ XW0a, const float* __restrict__ XW0b,
             const u16* __restrict__ G, const float* __restrict__ Af,
             const float* __restrict__ dd,
             const float* __restrict__ gb0, const float* __restrict__ gb1,
             u16* __restrict__ Ha, u16* __restrict__ Hb,
             const float* __restrict__ W0, const float* __restrict__ W1,
             u16* __restrict__ Wb0, u16* __restrict__ Wb1)
{
    const int bid = blockIdx.x;
    if (bid < 1024) gcnfix_body(bid, XW0a, XW0b, G, Af, dd, gb0, gb1, Ha, Hb);
    else            wcvt_body(bid - 1024, W0, W1, Wb0, Wb1);
}

// ---------------------------------------------------------------- gcnfix hop2 (standalone)
__global__ __launch_bounds__(256)
void k_gcnfix(const float* __restrict__ XW0a, const float* __restrict__ XW0b,
              const u16* __restrict__ G, const float* __restrict__ Af,
              const float* __restrict__ dd,
              const float* __restrict__ gb0, const float* __restrict__ gb1,
              u16* __restrict__ Ha, u16* __restrict__ Hb)
{
    gcnfix_body(blockIdx.x, XW0a, XW0b, G, Af, dd, gb0, gb1, Ha, Hb);
}

// ---------------------------------------------------------------- inception + gate + skip (bf16 weights in LDS)
__device__ __forceinline__ constexpr int wbase_of(int k) {
    return k == 2 ? 0 : k == 3 ? 520 : k == 6 ? 1296 : 2840;
}
__device__ __forceinline__ constexpr int ob_of(int k) {
    return k == 2 ? 0 : k == 3 ? 8 : k == 6 ? 16 : 24;
}

template<int KA, int KB>
__device__ __forceinline__ void conv_dual(const float* __restrict__ xsb,
                                          const u16* __restrict__ wfA,
                                          const u16* __restrict__ wgA,
                                          const u16* __restrict__ wfB,
                                          const u16* __restrict__ wgB,
                                          float fbA, float gbA, float fbB, float gbB,
                                          u16* __restrict__ GpA, u16* __restrict__ GpB,
                                          u16* __restrict__ GsA, u16* __restrict__ GsB)
{
    float afA[8], agA[8], afB[8], agB[8];
    #pragma unroll
    for (int i = 0; i < 8; ++i) {
        afA[i] = fbA; agA[i] = gbA;
        afB[i] = fbB; agB[i] = gbB;
    }
    for (int c = 0; c < 32; ++c) {
        float xw[24];
        const float* xr = xsb + c * 144;
        #pragma unroll
        for (int q = 0; q < 6; ++q) {
            f32x4 v = *(const f32x4*)(xr + q * 4);
            xw[q * 4 + 0] = v[0]; xw[q * 4 + 1] = v[1];
            xw[q * 4 + 2] = v[2]; xw[q * 4 + 3] = v[3];
        }
        {
            float wf[KA], wg[KA];
            const u16* pf = wfA + c * KA;
            const u16* pg = wgA + c * KA;
            #pragma unroll
            for (int j = 0; j < KA; ++j) { wf[j] = bf2f(pf[j]); wg[j] = bf2f(pg[j]); }
            #pragma unroll
            for (int li = 0; li < 8; ++li) {
                #pragma unroll
                for (int j = 0; j < KA; ++j) {
                    float xv = xw[li + 8 - (KA - 1) + 2 * j];
                    afA[li] = __fmaf_rn(xv, wf[j], afA[li]);
                    agA[li] = __fmaf_rn(xv, wg[j], agA[li]);
                }
            }
        }
        {
            float wf[KB], wg[KB];
            const u16* pf = wfB + c * KB;
            const u16* pg = wgB + c * KB;
            #pragma unroll
            for (int j = 0; j < KB; ++j) { wf[j] = bf2f(pf[j]); wg[j] = bf2f(pg[j]); }
            #pragma unroll
            for (int li = 0; li < 8; ++li) {
                #pragma unroll
                for (int j = 0; j < KB; ++j) {
                    float xv = xw[li + 8 - (KB - 1) + 2 * j];
                    afB[li] = __fmaf_rn(xv, wf[j], afB[li]);
                    agB[li] = __fmaf_rn(xv, wg[j], agB[li]);
                }
            }
        }
    }
    u16 oA[8], oB[8];
    #pragma unroll
    for (int i = 0; i < 8; ++i) {
        float e2 = __expf(2.f * afA[i]);
        float th = 1.f - __fdividef(2.f, e2 + 1.f);
        float sg = __fdividef(1.f, 1.f + __expf(-agA[i]));
        oA[i] = f2bf(th * sg);
        float e2b = __expf(2.f * afB[i]);
        float thb = 1.f - __fdividef(2.f, e2b + 1.f);
        float sgb = __fdividef(1.f, 1.f + __expf(-agB[i]));
        oB[i] = f2bf(thb * sgb);
    }
    uint4 uA, uB;
    uA.x = oA[0] | ((u32)oA[1] << 16); uA.y = oA[2] | ((u32)oA[3] << 16);
    uA.z = oA[4] | ((u32)oA[5] << 16); uA.w = oA[6] | ((u32)oA[7] << 16);
    uB.x = oB[0] | ((u32)oB[1] << 16); uB.y = oB[2] | ((u32)oB[3] << 16);
    uB.z = oB[4] | ((u32)oB[5] << 16); uB.w = oB[6] | ((u32)oB[7] << 16);
    *(uint4*)GpA = uA; *(uint4*)GpB = uB;
    *(uint4*)GsA = uA; *(uint4*)GsB = uB;
}

__global__ __launch_bounds__(256)
void k_incskip(const float* __restrict__ x,
               const float* __restrict__ fw2p, const float* __restrict__ fw3p,
               const float* __restrict__ fw6p, const float* __restrict__ fw7p,
               const float* __restrict__ fb2p, const float* __restrict__ fb3p,
               const float* __restrict__ fb6p, const float* __restrict__ fb7p,
               const float* __restrict__ gw2p, const float* __restrict__ gw3p,
               const float* __restrict__ gw6p, const float* __restrict__ gw7p,
               const float* __restrict__ gb2p, const float* __restrict__ gb3p,
               const float* __restrict__ gb6p, const float* __restrict__ gb7p,
               const float* __restrict__ sw,   const float* __restrict__ sb,
               const float* __restrict__ xskip,
               u16* __restrict__ G, float* __restrict__ outp)
{
    __shared__ alignas(16) float xs[32 * 144];       // 18.0 KB (guarded)
    __shared__ u16 wfl[4640], wgl[4640];             // 18.1 KB bf16 weights
    __shared__ float fbl[32], gbl[32];
    __shared__ alignas(16) u16 Gs[4096];             // 8 KB
    __shared__ float swl[64 * 33];                   // 8.4 KB
    __shared__ float sbl[64];
    const int tid = threadIdx.x;
    const int b = blockIdx.x >> 7, n = blockIdx.x & 127;

    for (int i = tid; i < 32 * 144; i += 256) xs[i] = 0.f;
    for (int g = tid; g < 4608; g += 256) {
        int rel, k, woff;
        const float *pf, *pg;
        if (g < 512)       { rel = g;        k = 2; woff = 0;    pf = fw2p; pg = gw2p; }
        else if (g < 1280) { rel = g - 512;  k = 3; woff = 520;  pf = fw3p; pg = gw3p; }
        else if (g < 2816) { rel = g - 1280; k = 6; woff = 1296; pf = fw6p; pg = gw6p; }
        else               { rel = g - 2816; k = 7; woff = 2840; pf = fw7p; pg = gw7p; }
        int ck = 32 * k;
        int oo = rel / ck, rem = rel % ck;
        int dst = woff + oo * (ck + 1) + rem;
        wfl[dst] = f2bf(pf[rel]);
        wgl[dst] = f2bf(pg[rel]);
    }
    for (int i = tid; i < 2048; i += 256) swl[(i >> 5) * 33 + (i & 31)] = sw[i];
    if (tid < 64) sbl[tid] = sb[tid];
    if (tid < 32) {
        int br = tid >> 3, oo = tid & 7;
        const float* pf = br == 0 ? fb2p : br == 1 ? fb3p : br == 2 ? fb6p : fb7p;
        const float* pg = br == 0 ? gb2p : br == 1 ? gb3p : br == 2 ? gb6p : gb7p;
        fbl[tid] = pf[oo]; gbl[tid] = pg[oo];
    }
    __syncthreads();
    const float* xb = x + (size_t)b * 524288 + n * 128;
    for (int p = 0; p < 4; ++p) {
        int chunk = p * 256 + tid;
        int c = chunk >> 5, l4 = (chunk & 31) * 4;
        *(f32x4*)&xs[c * 144 + 8 + l4] = *(const f32x4*)(xb + (size_t)c * 16384 + l4);
    }
    __syncthreads();

    {
        const int w = tid >> 6, lane = tid & 63;
        const int oo = lane >> 3, lL = lane & 7;
        const int h  = w & 1;
        const int l0 = h * 64 + lL * 8;
        const float* xsb = xs + l0;
        size_t gbase = ((size_t)b * 32 * 128 + n) * 128 + l0;
        if (w < 2) {
            constexpr int KA = 2, KB = 7;
            const int oA = ob_of(KA) + oo, oB = ob_of(KB) + oo;
            conv_dual<KA, KB>(xsb,
                wfl + wbase_of(KA) + oo * (32 * KA + 1), wgl + wbase_of(KA) + oo * (32 * KA + 1),
                wfl + wbase_of(KB) + oo * (32 * KB + 1), wgl + wbase_of(KB) + oo * (32 * KB + 1),
                fbl[oA], gbl[oA], fbl[oB], gbl[oB],
                G + gbase + (size_t)oA * 16384, G + gbase + (size_t)oB * 16384,
                Gs + oA * 128 + l0, Gs + oB * 128 + l0);
        } else {
            constexpr int KA = 3, KB = 6;
            const int oA = ob_of(KA) + oo, oB = ob_of(KB) + oo;
            conv_dual<KA, KB>(xsb,
                wfl + wbase_of(KA) + oo * (32 * KA + 1), wgl + wbase_of(KA) + oo * (32 * KA + 1),
                wfl + wbase_of(KB) + oo * (32 * KB + 1), wgl + wbase_of(KB) + oo * (32 * KB + 1),
                fbl[oA], gbl[oA], fbl[oB], gbl[oB],
                G + gbase + (size_t)oA * 16384, G + gbase + (size_t)oB * 16384,
                Gs + oA * 128 + l0, Gs + oB * 128 + l0);
        }
    }
    __syncthreads();

    const int sg = (tid & 15) * 4, l0s = (tid >> 4) * 8;
    float acc[4][8];
    #pragma unroll
    for (int si = 0; si < 4; ++si) {
        float bv = sbl[sg + si];
        #pragma unroll
        for (int li = 0; li < 8; ++li) acc[si][li] = bv;
    }
    for (int c = 0; c < 32; ++c) {
        uint4 gv = *(const uint4*)&Gs[c * 128 + l0s];
        float g[8];
        g[0] = __uint_as_float(gv.x << 16); g[1] = __uint_as_float(gv.x & 0xffff0000u);
        g[2] = __uint_as_float(gv.y << 16); g[3] = __uint_as_float(gv.y & 0xffff0000u);
        g[4] = __uint_as_float(gv.z << 16); g[5] = __uint_as_float(gv.z & 0xffff0000u);
        g[6] = __uint_as_float(gv.w << 16); g[7] = __uint_as_float(gv.w & 0xffff0000u);
        #pragma unroll
        for (int si = 0; si < 4; ++si) {
            float wv = swl[(sg + si) * 33 + c];
            #pragma unroll
            for (int li = 0; li < 8; ++li) acc[si][li] = __fmaf_rn(g[li], wv, acc[si][li]);
        }
    }
    #pragma unroll
    for (int si = 0; si < 4; ++si) {
        size_t e = ((size_t)(b * 64 + sg + si) * 128 + n) * 128 + l0s;
        f32x4 x0 = *(const f32x4*)(xskip + e);
        f32x4 x1 = *(const f32x4*)(xskip + e + 4);
        f32x4 r0, r1;
        r0[0] = acc[si][0] + x0[0]; r0[1] = acc[si][1] + x0[1];
        r0[2] = acc[si][2] + x0[2]; r0[3] = acc[si][3] + x0[3];
        r1[0] = acc[si][4] + x1[0]; r1[1] = acc[si][5] + x1[1];
        r1[2] = acc[si][6] + x1[2]; r1[3] = acc[si][7] + x1[3];
        *(f32x4*)(outp + e)     = r0;
        *(f32x4*)(outp + e + 4) = r1;
    }
}

// ---------------------------------------------------------------- fused mix1+mix2 + x-residual + LN partial sums (Y bf16)
__global__ __launch_bounds__(256)
void k_mix2ln(const u16* __restrict__ G,
              const u16* __restrict__ H1, const u16* __restrict__ H2,
              const u16* __restrict__ H1b, const u16* __restrict__ H2b,
              const float* __restrict__ mw1, const float* __restrict__ mb1,
              const float* __restrict__ mw2, const float* __restrict__ mb2,
              const float* __restrict__ x,
              u16* __restrict__ Y, float* __restrict__ partial)
{
    __shared__ alignas(16) u16 Gs[4096], H1s[4096], H2s[4096], H1bs[4096], H2bs[4096];
    __shared__ float wSg[32 * 33], wS11[32 * 33], wS12[32 * 33], wS21[32 * 33], wS22[32 * 33];
    __shared__ float mbl[32];
    const int tid = threadIdx.x;
    const int b = blockIdx.x >> 7, xn = blockIdx.x & 127;
    size_t base = (size_t)b * 524288 + xn * 128;
    for (int p = 0; p < 2; ++p) {
        int chunk = p * 256 + tid, c = chunk >> 4, l8 = (chunk & 15) * 8;
        size_t src = base + (size_t)c * 16384 + l8;
        *(uint4*)&Gs[c * 128 + l8]   = *(const uint4*)(G + src);
        *(uint4*)&H1s[c * 128 + l8]  = *(const uint4*)(H1 + src);
        *(uint4*)&H2s[c * 128 + l8]  = *(const uint4*)(H2 + src);
        *(uint4*)&H1bs[c * 128 + l8] = *(const uint4*)(H1b + src);
        *(uint4*)&H2bs[c * 128 + l8] = *(const uint4*)(H2b + src);
    }
    for (int i = tid; i < 1024; i += 256) {
        int o = i >> 5, c = i & 31;
        int d = o * 33 + c;
        wSg[d]  = mw1[o * 96 + c] + mw2[o * 96 + c];
        wS11[d] = mw1[o * 96 + 32 + c];
        wS12[d] = mw1[o * 96 + 64 + c];
        wS21[d] = mw2[o * 96 + 32 + c];
        wS22[d] = mw2[o * 96 + 64 + c];
    }
    if (tid < 32) mbl[tid] = mb1[tid] + mb2[tid];
    __syncthreads();
    const int og = (tid & 7) * 4, l0 = (tid >> 3) * 4;
    float acc[4][4];
    #pragma unroll
    for (int oi = 0; oi < 4; ++oi) {
        float bv = mbl[og + oi];
        acc[oi][0] = bv; acc[oi][1] = bv; acc[oi][2] = bv; acc[oi][3] = bv;
    }
    for (int c = 0; c < 32; ++c) {
        uint2 ga = *(const uint2*)&Gs[c * 128 + l0];
        uint2 h1 = *(const uint2*)&H1s[c * 128 + l0];
        uint2 h2 = *(const uint2*)&H2s[c * 128 + l0];
        uint2 j1 = *(const uint2*)&H1bs[c * 128 + l0];
        uint2 j2 = *(const uint2*)&H2bs[c * 128 + l0];
        float gv[4], v1[4], v2[4], u1[4], u2[4];
        gv[0] = __uint_as_float(ga.x << 16); gv[1] = __uint_as_float(ga.x & 0xffff0000u);
        gv[2] = __uint_as_float(ga.y << 16); gv[3] = __uint_as_float(ga.y & 0xffff0000u);
        v1[0] = __uint_as_float(h1.x << 16); v1[1] = __uint_as_float(h1.x & 0xffff0000u);
        v1[2] = __uint_as_float(h1.y << 16); v1[3] = __uint_as_float(h1.y & 0xffff0000u);
        v2[0] = __uint_as_float(h2.x << 16); v2[1] = __uint_as_float(h2.x & 0xffff0000u);
        v2[2] = __uint_as_float(h2.y << 16); v2[3] = __uint_as_float(h2.y & 0xffff0000u);
        u1[0] = __uint_as_float(j1.x << 16); u1[1] = __uint_as_float(j1.x & 0xffff0000u);
        u1[2] = __uint_as_float(j1.y << 16); u1[3] = __uint_as_float(j1.y & 0xffff0000u);
        u2[0] = __uint_as_float(j2.x << 16); u2[1] = __uint_as_float(j2.x & 0xffff0000u);
        u2[2] = __uint_as_float(j2.y << 16); u2[3] = __uint_as_float(j2.y & 0xffff0000u);
        #pragma unroll
        for (int oi = 0; oi < 4; ++oi) {
            int d = (og + oi) * 33 + c;
            float a0 = wSg[d], a1 = wS11[d], a2 = wS12[d], a3 = wS21[d], a4 = wS22[d];
            #pragma unroll
            for (int li = 0; li < 4; ++li)
                acc[oi][li] += gv[li] * a0 + v1[li] * a1 + v2[li] * a2
                             + u1[li] * a3 + u2[li] * a4;
        }
    }
    float s = 0.f, ss = 0.f;
    #pragma unroll
    for (int oi = 0; oi < 4; ++oi) {
        size_t e = ((size_t)(b * 32 + og + oi) * 128 + xn) * 128 + l0;
        f32x4 xv = *(const f32x4*)(x + e);
        float y0 = acc[oi][0] + xv[0];
        float y1 = acc[oi][1] + xv[1];
        float y2 = acc[oi][2] + xv[2];
        float y3 = acc[oi][3] + xv[3];
        s  += y0 + y1 + y2 + y3;
        ss += y0 * y0 + y1 * y1 + y2 * y2 + y3 * y3;
        uint2 rr;
        rr.x = cvt2bf(y0, y1);
        rr.y = cvt2bf(y2, y3);
        *(uint2*)(Y + e) = rr;
    }
    #pragma unroll
    for (int o = 32; o > 0; o >>= 1) {
        s  += __shfl_down(s,  o, 64);
        ss += __shfl_down(ss, o, 64);
    }
    __shared__ float sred[8];
    int w = tid >> 6;
    if ((tid & 63) == 0) { sred[w * 2] = s; sred[w * 2 + 1] = ss; }
    __syncthreads();
    if (tid == 0) {
        partial[blockIdx.x * 2]     = sred[0] + sred[2] + sred[4] + sred[6];
        partial[blockIdx.x * 2 + 1] = sred[1] + sred[3] + sred[5] + sred[7];
    }
}

// ---------------------------------------------------------------- LayerNorm finalize (Y bf16)
__global__ __launch_bounds__(256)
void k_lnnorm(const u16* __restrict__ Y,
              const float* __restrict__ partial, const int* __restrict__ idxp,
              const float* __restrict__ lnw, const float* __restrict__ lnb,
              float* __restrict__ outx)
{
    const int tid = threadIdx.x;
    const int b = blockIdx.x >> 7, chunk = blockIdx.x & 127;
    float s = 0.f, ss = 0.f;
    if (tid < 128) {
        s  = partial[(b * 128 + tid) * 2];
        ss = partial[(b * 128 + tid) * 2 + 1];
    }
    #pragma unroll
    for (int o = 32; o > 0; o >>= 1) {
        s  += __shfl_down(s,  o, 64);
        ss += __shfl_down(ss, o, 64);
    }
    __shared__ float sred[4];
    __shared__ float mv[2];
    if ((tid & 63) == 0 && tid < 128) { sred[(tid >> 6) * 2] = s; sred[(tid >> 6) * 2 + 1] = ss; }
    __syncthreads();
    if (tid == 0) {
        float S = sred[0] + sred[2], SS = sred[1] + sred[3];
        float mean = S * (1.f / 524288.f);
        float var = SS * (1.f / 524288.f) - mean * mean;
        mv[0] = mean; mv[1] = rsqrtf(var + 1e-5f);
    }
    __syncthreads();
    const float mean = mv[0], rstd = mv[1];
    #pragma unroll
    for (int q = 0; q < 4; ++q) {
        int ib = chunk * 4096 + q * 1024 + tid * 4;
        size_t e = (size_t)b * 524288 + ib;
        uint2 yv2 = *(const uint2*)(Y + e);
        float y[4];
        y[0] = __uint_as_float(yv2.x << 16); y[1] = __uint_as_float(yv2.x & 0xffff0000u);
        y[2] = __uint_as_float(yv2.y << 16); y[3] = __uint_as_float(yv2.y & 0xffff0000u);
        int c = ib >> 14, xn = (ib >> 7) & 127, l = ib & 127;
        int ix = idxp[xn];
        size_t we = ((size_t)c * 128 + ix) * 128 + l;
        f32x4 wv = *(const f32x4*)(lnw + we);
        f32x4 bv = *(const f32x4*)(lnb + we);
        f32x4 r;
        #pragma unroll
        for (int j = 0; j < 4; ++j)
            r[j] = (y[j] - mean) * rstd * wv[j] + bv[j];
        *(f32x4*)(outx + e) = r;
    }
}

// ---------------------------------------------------------------- launcher
extern "C" void kernel_launch(void* const* d_in, const int* in_sizes, int n_in,
                              void* d_out, int out_size, void* d_ws, size_t ws_size,
                              hipStream_t stream)
{
    (void)in_sizes; (void)n_in; (void)out_size; (void)ws_size;
    const float* x      = (const float*)d_in[0];
    const float* xskip  = (const float*)d_in[1];
    const float* A      = (const float*)d_in[2];
    const int*   idxp   = (const int*)d_in[3];
    const float* fw2p = (const float*)d_in[4];  const float* fb2p = (const float*)d_in[5];
    const float* fw3p = (const float*)d_in[6];  const float* fb3p = (const float*)d_in[7];
    const float* fw6p = (const float*)d_in[8];  const float* fb6p = (const float*)d_in[9];
    const float* fw7p = (const float*)d_in[10]; const float* fb7p = (const float*)d_in[11];
    const float* gw2p = (const float*)d_in[12]; const float* gb2p = (const float*)d_in[13];
    const float* gw3p = (const float*)d_in[14]; const float* gb3p = (const float*)d_in[15];
    const float* gw6p = (const float*)d_in[16]; const float* gb6p = (const float*)d_in[17];
    const float* gw7p = (const float*)d_in[18]; const float* gb7p = (const float*)d_in[19];
    const float* sw   = (const float*)d_in[20]; const float* sb   = (const float*)d_in[21];
    const float* mp1_gw = (const float*)d_in[22]; const float* mp1_gb = (const float*)d_in[23];
    const float* mp1_mw = (const float*)d_in[24]; const float* mp1_mb = (const float*)d_in[25];
    const float* mp2_gw = (const float*)d_in[26]; const float* mp2_gb = (const float*)d_in[27];
    const float* mp2_mw = (const float*)d_in[28]; const float* mp2_mb = (const float*)d_in[29];
    const float* lnw = (const float*)d_in[30]; const float* lnb = (const float*)d_in[31];

    char* wsb = (char*)d_ws;
    float* out_x  = (float*)d_out;
    float* out_sk = out_x + 8388608;

    const size_t MB16 = 16777216, MB33 = 33554432;
    u16*   G    = (u16*)(wsb);
    u16*   H1   = (u16*)(wsb + MB16);
    u16*   H1b  = (u16*)(wsb + 2 * MB16);
    u16*   H2   = (u16*)(wsb + 3 * MB16);
    u16*   H2b  = (u16*)(wsb + 4 * MB16);
    u16*   Wb0  = (u16*)(wsb + 5 * MB16);
    u16*   Wb1  = (u16*)(wsb + 5 * MB16 + MB33);
    u16*   Yb   = (u16*)Wb0;                        // bf16 Y, reuse after hop-2 GEMM
    float* XW0a = (float*)(wsb + 5 * MB16 + 2 * MB33);
    float* XW0b = (float*)(wsb + 5 * MB16 + 2 * MB33 + 2097152);
    float* part = (float*)(wsb + 5 * MB16 + 2 * MB33 + 4194304);
    float* dd   = (float*)(wsb + 5 * MB16 + 2 * MB33 + 4194304 + 16384);

    // 1: wcvt hop1 + prep (zero-LDS, full occupancy)
    k_wcvtprep<<<16385, 256, 0, stream>>>(mp1_gw, mp2_gw, Wb0, Wb1, A, dd);
    // 2: inception + gate + skip (3 blocks/CU with bf16 weights)
    k_incskip<<<2048, 256, 0, stream>>>(x, fw2p, fw3p, fw6p, fw7p, fb2p, fb3p, fb6p, fb7p,
                                        gw2p, gw3p, gw6p, gw7p, gb2p, gb3p, gb6p, gb7p,
                                        sw, sb, xskip, G, out_sk);
    // 3: GEMM hop1
    k_gemm2g<<<256, 512, 0, stream>>>(G, G, Wb0, Wb1, G, mp1_gb, mp2_gb,
                                      H1, H1b, XW0a, XW0b);
    // 4: gcnfix hop1 | wcvt hop2 (zero-LDS)
    k_mega2<<<17408, 256, 0, stream>>>(XW0a, XW0b, G, A, dd, mp1_gb, mp2_gb,
                                       H1, H1b, mp1_gw + MB16, mp2_gw + MB16, Wb0, Wb1);
    // 5: GEMM hop2
    k_gemm2g<<<256, 512, 0, stream>>>(H1, H1b, Wb0, Wb1, G, mp1_gb + 4096, mp2_gb + 4096,
                                      H2, H2b, XW0a, XW0b);
    // 6: gcnfix hop2
    k_gcnfix<<<1024, 256, 0, stream>>>(XW0a, XW0b, G, A, dd,
                                       mp1_gb + 4096, mp2_gb + 4096, H2, H2b);
    // 7: fused channel-mix + residual + LN partials
    k_mix2ln<<<2048, 256, 0, stream>>>(G, H1, H2, H1b, H2b, mp1_mw, mp1_mb,
                                       mp2_mw, mp2_mb, x, Yb, part);
    // 8: LN finalize
    k_lnnorm<<<2048, 256, 0, stream>>>(Yb, part, idxp, lnw, lnb, out_x);
}

// Round 15
// 643.131 us; speedup vs baseline: 1.1037x; 1.1037x over previous
//
#include <hip/hip_runtime.h>
#include <stdint.h>

typedef unsigned short u16;
typedef unsigned int   u32;
typedef __attribute__((ext_vector_type(4))) float f32x4;
typedef __attribute__((ext_vector_type(8))) short bf16x8;

__device__ __forceinline__ u16 f2bf(float f) {
    u32 i = __float_as_uint(f);
    u32 r = (i + 0x7fffu + ((i >> 16) & 1u)) >> 16;   // RNE
    return (u16)r;
}
__device__ __forceinline__ float bf2f(u16 u) {
    return __uint_as_float(((u32)u) << 16);
}
__device__ __forceinline__ u32 cvt2bf(float a, float b) {
    u32 r;
    asm("v_cvt_pk_bf16_f32 %0, %1, %2" : "=v"(r) : "v"(a), "v"(b));
    return r;
}

#define GLOAD16(g, l) __builtin_amdgcn_global_load_lds( \
    (const __attribute__((address_space(1))) void*)(g), \
    (__attribute__((address_space(3))) void*)(l), 16, 0, 0)

#define RAW_BARRIER()  asm volatile("s_barrier" ::: "memory")
#define VMCNT(n)       asm volatile("s_waitcnt vmcnt(" #n ")" ::: "memory")

// ---------------------------------------------------------------- GEMM + fused GCN-self epilogue (R8/R11 best config)
// 256x256 tile, BK=32, 512 thr (8 waves 2x4). 4-deep LDS tile rotation,
// stage 3 tiles ahead, ONE vmcnt(8) + ONE raw s_barrier per K-tile.
__global__ __launch_bounds__(512, 1)
void k_gemm2g(const u16* __restrict__ A0, const u16* __restrict__ A1,
              const u16* __restrict__ B0, const u16* __restrict__ B1,
              const u16* __restrict__ Gres,
              const float* __restrict__ gb0, const float* __restrict__ gb1,
              u16* __restrict__ Ha, u16* __restrict__ Hb,
              float* __restrict__ XW0a, float* __restrict__ XW0b)
{
    __shared__ alignas(16) u16 LDS[65536];      // 128 KB = 4 tile-buffers x 16384 u16
    const int NT = 128;                          // K / BK = 4096 / 32
    const int tid  = threadIdx.x;
    const int lane = tid & 63;
    const int wid  = tid >> 6;
    const int wr = wid >> 2, wc = wid & 3;       // 2 x 4 wave grid, per-wave C 128x64

    const int bid = blockIdx.x;
    const int swz = (bid & 7) * 32 + (bid >> 3);
    const int z   = swz >> 7;
    const int rem = swz & 127;
    const int bm = (rem >> 4) * 256;             // 8 m-tiles
    const int bn = (rem & 15) * 256;             // 16 n-tiles

    const u16* Ap = (z ? A1 : A0) + (size_t)bm * 4096;
    const u16* Bp = (z ? B1 : B0) + (size_t)bn * 4096;

    int aoff[8], boff[4];
    #pragma unroll
    for (int i = 0; i < 8; ++i) {
        int row = wr * 128 + i * 16 + (lane & 15);
        int sp  = (lane >> 4) ^ ((row >> 1) & 3);
        aoff[i] = row * 32 + sp * 8;
    }
    #pragma unroll
    for (int j = 0; j < 4; ++j) {
        int row = wc * 64 + j * 16 + (lane & 15);
        int sp  = (lane >> 4) ^ ((row >> 1) & 3);
        boff[j] = row * 32 + sp * 8;
    }

    auto stage = [&](int t) {
        if (t >= NT) return;
        const int k0  = t << 5;
        u16* buf = LDS + ((t & 3) << 14);
        #pragma unroll
        for (int h = 0; h < 2; ++h) {
            const int c  = tid + h * 512;
            const int r  = c >> 2;
            const int sl = (c & 3) ^ ((r >> 1) & 3);
            GLOAD16(Ap + (size_t)r * 4096 + k0 + sl * 8, buf + c * 8);
            GLOAD16(Bp + (size_t)r * 4096 + k0 + sl * 8, buf + 8192 + c * 8);
        }
    };

    f32x4 acc[8][4] = {};

    auto compute = [&](int t) {
        const u16* buf = LDS + ((t & 3) << 14);
        bf16x8 af[8], bf[4];
        #pragma unroll
        for (int j = 0; j < 4; ++j) bf[j] = *(const bf16x8*)(buf + 8192 + boff[j]);
        #pragma unroll
        for (int i = 0; i < 8; ++i) af[i] = *(const bf16x8*)(buf + aoff[i]);
        __builtin_amdgcn_s_setprio(1);
        #pragma unroll
        for (int i = 0; i < 8; ++i)
            #pragma unroll
            for (int j = 0; j < 4; ++j)
                acc[i][j] = __builtin_amdgcn_mfma_f32_16x16x32_bf16(af[i], bf[j], acc[i][j], 0, 0, 0);
        __builtin_amdgcn_s_setprio(0);
    };

    stage(0); stage(1); stage(2);
    for (int t = 0; t < NT - 3; ++t) {
        VMCNT(8);
        RAW_BARRIER();
        stage(t + 3);
        compute(t);
    }
    VMCNT(8);  RAW_BARRIER(); compute(NT - 3);
    VMCNT(4);  RAW_BARRIER(); compute(NT - 2);
    VMCNT(0);  RAW_BARRIER(); compute(NT - 1);

    // ---------------- epilogue
    const int orow = (lane >> 4) * 4, ocol = lane & 15;
    const float* gbv = z ? gb1 : gb0;
    u16* H = z ? Hb : Ha;

    #pragma unroll
    for (int j = 0; j < 4; ++j) {
        const int o = bn + wc * 64 + j * 16 + ocol;
        const float gbo = gbv[o];
        #pragma unroll
        for (int i = 0; i < 8; ++i) {
            const int rbase = bm + wr * 128 + i * 16 + orow;
            #pragma unroll
            for (int v = 0; v < 4; ++v) {
                const size_t e = (size_t)(rbase + v) * 4096 + o;
                float g = bf2f(Gres[e]);
                H[e] = f2bf(__fmaf_rn(0.05f, g, acc[i][j][v] + gbo));
            }
        }
    }
    if (bm == 0 && wr == 0) {
        float* XW0 = z ? XW0b : XW0a;
        #pragma unroll
        for (int i = 0; i < 8; ++i) {
            #pragma unroll
            for (int j = 0; j < 4; ++j) {
                float* cp = XW0 + (size_t)(i * 16 + orow) * 4096 + (bn + wc * 64 + j * 16 + ocol);
                #pragma unroll
                for (int v = 0; v < 4; ++v)
                    cp[(size_t)v * 4096] = acc[i][j][v];
            }
        }
    }
}

// ---------------------------------------------------------------- device helpers for fused kernels
__device__ __forceinline__ void wcvt_body(int wb, const float* __restrict__ W0,
                                          const float* __restrict__ W1,
                                          u16* __restrict__ Wb0, u16* __restrict__ Wb1)
{
    int half = wb >> 13;
    const float* W = half ? W1 : W0;
    u16* Wb = half ? Wb1 : Wb0;
    size_t e = ((size_t)(wb & 8191) * 256 + threadIdx.x) * 8;
    f32x4 a = *(const f32x4*)(W + e);
    f32x4 b = *(const f32x4*)(W + e + 4);
    uint4 r;
    r.x = cvt2bf(a[0], a[1]); r.y = cvt2bf(a[2], a[3]);
    r.z = cvt2bf(b[0], b[1]); r.w = cvt2bf(b[2], b[3]);
    *(uint4*)(Wb + e) = r;
}

__device__ __forceinline__ void prep_body(const float* __restrict__ A, float* dd)
{
    int r = threadIdx.x;
    if (r >= 128) return;
    int cc = 0, cr = 0;
    for (int j = 0; j < 128; ++j) {
        if (j == r) continue;
        if (A[(j << 7) + r] != 0.f) cc++;
        if (A[(r << 7) + j] != 0.f) cr++;
    }
    float d1 = 1.f + (float)cc, d2 = 1.f + (float)cr;
    dd[r]       = rsqrtf(d1); dd[128 + r] = 1.f / d1;   // dis1, inv1
    dd[256 + r] = rsqrtf(d2); dd[384 + r] = 1.f / d2;   // dis2, inv2
}

__device__ __forceinline__ void gcnfix_body(int fb, const float* __restrict__ XW0a,
              const float* __restrict__ XW0b,
              const u16* __restrict__ G, const float* __restrict__ Af,
              const float* __restrict__ dd,
              const float* __restrict__ gb0, const float* __restrict__ gb1,
              u16* __restrict__ Ha, u16* __restrict__ Hb)
{
    const int prob = fb >> 9;          // 0: mp1 (A), 1: mp2 (A^T)
    const int rem  = fb & 511;
    const int t4 = rem * 256 + threadIdx.x;
    const int r = t4 >> 10, og = (t4 & 1023) << 2;
    const float* XW0 = prob ? XW0b : XW0a;
    const float* dis = prob ? dd + 256 : dd;
    const float* inv = prob ? dd + 384 : dd + 128;
    const float* gb  = prob ? gb1  : gb0;
    u16* H = prob ? Hb : Ha;

    const size_t e = ((size_t)r << 12) + og;
    f32x4 xw = *(const f32x4*)(XW0 + e);
    f32x4 s = {0.f, 0.f, 0.f, 0.f};
    for (int j = 0; j < 128; ++j) {
        float av = prob ? Af[(r << 7) + j] : Af[(j << 7) + r];
        float wv = ((av != 0.f) && (j != r)) ? dis[j] : 0.f;
        f32x4 xv = *(const f32x4*)(XW0 + ((size_t)j << 12) + og);
        #pragma unroll
        for (int q = 0; q < 4; ++q) s[q] = __fmaf_rn(wv, xv[q], s[q]);
    }
    const float iv = inv[r], dr = dis[r];
    f32x4 gb4 = *(const f32x4*)(gb + og);
    uint2 gv = *(const uint2*)(G + e);
    float g0 = __uint_as_float(gv.x << 16), g1 = __uint_as_float(gv.x & 0xffff0000u);
    float g2 = __uint_as_float(gv.y << 16), g3 = __uint_as_float(gv.y & 0xffff0000u);
    float y0 = __fmaf_rn(0.05f, g0, __fmaf_rn(dr, s[0], xw[0] * iv) + gb4[0]);
    float y1 = __fmaf_rn(0.05f, g1, __fmaf_rn(dr, s[1], xw[1] * iv) + gb4[1]);
    float y2 = __fmaf_rn(0.05f, g2, __fmaf_rn(dr, s[2], xw[2] * iv) + gb4[2]);
    float y3 = __fmaf_rn(0.05f, g3, __fmaf_rn(dr, s[3], xw[3] * iv) + gb4[3]);
    uint2 rr;
    rr.x = cvt2bf(y0, y1);
    rr.y = cvt2bf(y2, y3);
    *(uint2*)(H + e) = rr;
}

// ---------------------------------------------------------------- inception + gate + skip (fused body, f32 weights)
__device__ __forceinline__ constexpr int wbase_of(int k) {
    return k == 2 ? 0 : k == 3 ? 520 : k == 6 ? 1296 : 2840;
}
__device__ __forceinline__ constexpr int ob_of(int k) {
    return k == 2 ? 0 : k == 3 ? 8 : k == 6 ? 16 : 24;
}

template<int KA, int KB>
__device__ __forceinline__ void conv_dual(const float* __restrict__ xsb,
                                          const float* __restrict__ wfA,
                                          const float* __restrict__ wgA,
                                          const float* __restrict__ wfB,
                                          const float* __restrict__ wgB,
                                          float fbA, float gbA, float fbB, float gbB,
                                          u16* __restrict__ GpA, u16* __restrict__ GpB,
                                          u16* __restrict__ GsA, u16* __restrict__ GsB)
{
    float afA[8], agA[8], afB[8], agB[8];
    #pragma unroll
    for (int i = 0; i < 8; ++i) {
        afA[i] = fbA; agA[i] = gbA;
        afB[i] = fbB; agB[i] = gbB;
    }
    for (int c = 0; c < 32; ++c) {
        float xw[24];
        const float* xr = xsb + c * 144;
        #pragma unroll
        for (int q = 0; q < 6; ++q) {
            f32x4 v = *(const f32x4*)(xr + q * 4);
            xw[q * 4 + 0] = v[0]; xw[q * 4 + 1] = v[1];
            xw[q * 4 + 2] = v[2]; xw[q * 4 + 3] = v[3];
        }
        {
            float wf[KA], wg[KA];
            const float* pf = wfA + c * KA;
            const float* pg = wgA + c * KA;
            #pragma unroll
            for (int j = 0; j < KA; ++j) { wf[j] = pf[j]; wg[j] = pg[j]; }
            #pragma unroll
            for (int li = 0; li < 8; ++li) {
                #pragma unroll
                for (int j = 0; j < KA; ++j) {
                    float xv = xw[li + 8 - (KA - 1) + 2 * j];
                    afA[li] = __fmaf_rn(xv, wf[j], afA[li]);
                    agA[li] = __fmaf_rn(xv, wg[j], agA[li]);
                }
            }
        }
        {
            float wf[KB], wg[KB];
            const float* pf = wfB + c * KB;
            const float* pg = wgB + c * KB;
            #pragma unroll
            for (int j = 0; j < KB; ++j) { wf[j] = pf[j]; wg[j] = pg[j]; }
            #pragma unroll
            for (int li = 0; li < 8; ++li) {
                #pragma unroll
                for (int j = 0; j < KB; ++j) {
                    float xv = xw[li + 8 - (KB - 1) + 2 * j];
                    afB[li] = __fmaf_rn(xv, wf[j], afB[li]);
                    agB[li] = __fmaf_rn(xv, wg[j], agB[li]);
                }
            }
        }
    }
    u16 oA[8], oB[8];
    #pragma unroll
    for (int i = 0; i < 8; ++i) {
        float e2 = __expf(2.f * afA[i]);
        float th = 1.f - __fdividef(2.f, e2 + 1.f);
        float sg = __fdividef(1.f, 1.f + __expf(-agA[i]));
        oA[i] = f2bf(th * sg);
        float e2b = __expf(2.f * afB[i]);
        float thb = 1.f - __fdividef(2.f, e2b + 1.f);
        float sgb = __fdividef(1.f, 1.f + __expf(-agB[i]));
        oB[i] = f2bf(thb * sgb);
    }
    uint4 uA, uB;
    uA.x = oA[0] | ((u32)oA[1] << 16); uA.y = oA[2] | ((u32)oA[3] << 16);
    uA.z = oA[4] | ((u32)oA[5] << 16); uA.w = oA[6] | ((u32)oA[7] << 16);
    uB.x = oB[0] | ((u32)oB[1] << 16); uB.y = oB[2] | ((u32)oB[3] << 16);
    uB.z = oB[4] | ((u32)oB[5] << 16); uB.w = oB[6] | ((u32)oB[7] << 16);
    *(uint4*)GpA = uA; *(uint4*)GpB = uB;
    *(uint4*)GsA = uA; *(uint4*)GsB = uB;
}

// ---------------------------------------------------------------- mega1: incskip | wcvt hop1 | prep
__global__ __launch_bounds__(256)
void k_mega1(const float* __restrict__ x,
             const float* __restrict__ fw2p, const float* __restrict__ fw3p,
             const float* __restrict__ fw6p, const float* __restrict__ fw7p,
             const float* __restrict__ fb2p, const float* __restrict__ fb3p,
             const float* __restrict__ fb6p, const float* __restrict__ fb7p,
             const float* __restrict__ gw2p, const float* __restrict__ gw3p,
             const float* __restrict__ gw6p, const float* __restrict__ gw7p,
             const float* __restrict__ gb2p, const float* __restrict__ gb3p,
             const float* __restrict__ gb6p, const float* __restrict__ gb7p,
             const float* __restrict__ sw,   const float* __restrict__ sb,
             const float* __restrict__ xskip,
             u16* __restrict__ G, float* __restrict__ outp,
             const float* __restrict__ W0, const float* __restrict__ W1,
             u16* __restrict__ Wb0, u16* __restrict__ Wb1,
             const float* __restrict__ A, float* __restrict__ dd)
{
    const int bid = blockIdx.x;
    if (bid >= 2048) {
        if (bid < 18432) wcvt_body(bid - 2048, W0, W1, Wb0, Wb1);
        else             prep_body(A, dd);
        return;
    }
    __shared__ alignas(16) float xs[32 * 144];
    __shared__ float wfl[4640], wgl[4640];
    __shared__ float fbl[32], gbl[32];
    __shared__ alignas(16) u16 Gs[4096];
    __shared__ float swl[64 * 33];
    __shared__ float sbl[64];
    const int tid = threadIdx.x;
    const int b = bid >> 7, n = bid & 127;

    for (int i = tid; i < 32 * 144; i += 256) xs[i] = 0.f;
    for (int g = tid; g < 4608; g += 256) {
        int rel, k, woff;
        const float *pf, *pg;
        if (g < 512)       { rel = g;        k = 2; woff = 0;    pf = fw2p; pg = gw2p; }
        else if (g < 1280) { rel = g - 512;  k = 3; woff = 520;  pf = fw3p; pg = gw3p; }
        else if (g < 2816) { rel = g - 1280; k = 6; woff = 1296; pf = fw6p; pg = gw6p; }
        else               { rel = g - 2816; k = 7; woff = 2840; pf = fw7p; pg = gw7p; }
        int ck = 32 * k;
        int oo = rel / ck, rem = rel % ck;
        int dst = woff + oo * (ck + 1) + rem;
        wfl[dst] = pf[rel];
        wgl[dst] = pg[rel];
    }
    for (int i = tid; i < 2048; i += 256) swl[(i >> 5) * 33 + (i & 31)] = sw[i];
    if (tid < 64) sbl[tid] = sb[tid];
    if (tid < 32) {
        int br = tid >> 3, oo = tid & 7;
        const float* pf = br == 0 ? fb2p : br == 1 ? fb3p : br == 2 ? fb6p : fb7p;
        const float* pg = br == 0 ? gb2p : br == 1 ? gb3p : br == 2 ? gb6p : gb7p;
        fbl[tid] = pf[oo]; gbl[tid] = pg[oo];
    }
    __syncthreads();
    const float* xb = x + (size_t)b * 524288 + n * 128;
    for (int p = 0; p < 4; ++p) {
        int chunk = p * 256 + tid;
        int c = chunk >> 5, l4 = (chunk & 31) * 4;
        *(f32x4*)&xs[c * 144 + 8 + l4] = *(const f32x4*)(xb + (size_t)c * 16384 + l4);
    }
    __syncthreads();

    {
        const int w = tid >> 6, lane = tid & 63;
        const int oo = lane >> 3, lL = lane & 7;
        const int h  = w & 1;
        const int l0 = h * 64 + lL * 8;
        const float* xsb = xs + l0;
        size_t gbase = ((size_t)b * 32 * 128 + n) * 128 + l0;
        if (w < 2) {
            constexpr int KA = 2, KB = 7;
            const int oA = ob_of(KA) + oo, oB = ob_of(KB) + oo;
            conv_dual<KA, KB>(xsb,
                wfl + wbase_of(KA) + oo * (32 * KA + 1), wgl + wbase_of(KA) + oo * (32 * KA + 1),
                wfl + wbase_of(KB) + oo * (32 * KB + 1), wgl + wbase_of(KB) + oo * (32 * KB + 1),
                fbl[oA], gbl[oA], fbl[oB], gbl[oB],
                G + gbase + (size_t)oA * 16384, G + gbase + (size_t)oB * 16384,
                Gs + oA * 128 + l0, Gs + oB * 128 + l0);
        } else {
            constexpr int KA = 3, KB = 6;
            const int oA = ob_of(KA) + oo, oB = ob_of(KB) + oo;
            conv_dual<KA, KB>(xsb,
                wfl + wbase_of(KA) + oo * (32 * KA + 1), wgl + wbase_of(KA) + oo * (32 * KA + 1),
                wfl + wbase_of(KB) + oo * (32 * KB + 1), wgl + wbase_of(KB) + oo * (32 * KB + 1),
                fbl[oA], gbl[oA], fbl[oB], gbl[oB],
                G + gbase + (size_t)oA * 16384, G + gbase + (size_t)oB * 16384,
                Gs + oA * 128 + l0, Gs + oB * 128 + l0);
        }
    }
    __syncthreads();

    const int sg = (tid & 15) * 4, l0s = (tid >> 4) * 8;
    float acc[4][8];
    #pragma unroll
    for (int si = 0; si < 4; ++si) {
        float bv = sbl[sg + si];
        #pragma unroll
        for (int li = 0; li < 8; ++li) acc[si][li] = bv;
    }
    for (int c = 0; c < 32; ++c) {
        uint4 gv = *(const uint4*)&Gs[c * 128 + l0s];
        float g[8];
        g[0] = __uint_as_float(gv.x << 16); g[1] = __uint_as_float(gv.x & 0xffff0000u);
        g[2] = __uint_as_float(gv.y << 16); g[3] = __uint_as_float(gv.y & 0xffff0000u);
        g[4] = __uint_as_float(gv.z << 16); g[5] = __uint_as_float(gv.z & 0xffff0000u);
        g[6] = __uint_as_float(gv.w << 16); g[7] = __uint_as_float(gv.w & 0xffff0000u);
        #pragma unroll
        for (int si = 0; si < 4; ++si) {
            float wv = swl[(sg + si) * 33 + c];
            #pragma unroll
            for (int li = 0; li < 8; ++li) acc[si][li] = __fmaf_rn(g[li], wv, acc[si][li]);
        }
    }
    #pragma unroll
    for (int si = 0; si < 4; ++si) {
        size_t e = ((size_t)(b * 64 + sg + si) * 128 + n) * 128 + l0s;
        f32x4 x0 = *(const f32x4*)(xskip + e);
        f32x4 x1 = *(const f32x4*)(xskip + e + 4);
        f32x4 r0, r1;
        r0[0] = acc[si][0] + x0[0]; r0[1] = acc[si][1] + x0[1];
        r0[2] = acc[si][2] + x0[2]; r0[3] = acc[si][3] + x0[3];
        r1[0] = acc[si][4] + x1[0]; r1[1] = acc[si][5] + x1[1];
        r1[2] = acc[si][6] + x1[2]; r1[3] = acc[si][7] + x1[3];
        *(f32x4*)(outp + e)     = r0;
        *(f32x4*)(outp + e + 4) = r1;
    }
}

// ---------------------------------------------------------------- mega2: gcnfix hop1 | wcvt hop2
__global__ __launch_bounds__(256)
void k_mega2(const float* __restrict__ XW0a, const float* __restrict__ XW0b,
             const u16* __restrict__ G, const float* __restrict__ Af,
             const float* __restrict__ dd,
             const float* __restrict__ gb0, const float* __restrict__ gb1,
             u16* __restrict__ Ha, u16* __restrict__ Hb,
             const float* __restrict__ W0, const float* __restrict__ W1,
             u16* __restrict__ Wb0, u16* __restrict__ Wb1)
{
    const int bid = blockIdx.x;
    if (bid < 1024) gcnfix_body(bid, XW0a, XW0b, G, Af, dd, gb0, gb1, Ha, Hb);
    else            wcvt_body(bid - 1024, W0, W1, Wb0, Wb1);
}

// ---------------------------------------------------------------- gcnfix hop2 (standalone)
__global__ __launch_bounds__(256)
void k_gcnfix(const float* __restrict__ XW0a, const float* __restrict__ XW0b,
              const u16* __restrict__ G, const float* __restrict__ Af,
              const float* __restrict__ dd,
              const float* __restrict__ gb0, const float* __restrict__ gb1,
              u16* __restrict__ Ha, u16* __restrict__ Hb)
{
    gcnfix_body(blockIdx.x, XW0a, XW0b, G, Af, dd, gb0, gb1, Ha, Hb);
}

// ---------------------------------------------------------------- fused mix1+mix2 + x-residual + LN partial sums (Y bf16)
__global__ __launch_bounds__(256)
void k_mix2ln(const u16* __restrict__ G,
              const u16* __restrict__ H1, const u16* __restrict__ H2,
              const u16* __restrict__ H1b, const u16* __restrict__ H2b,
              const float* __restrict__ mw1, const float* __restrict__ mb1,
              const float* __restrict__ mw2, const float* __restrict__ mb2,
              const float* __restrict__ x,
              u16* __restrict__ Y, float* __restrict__ partial)
{
    __shared__ alignas(16) u16 Gs[4096], H1s[4096], H2s[4096], H1bs[4096], H2bs[4096];
    __shared__ float wSg[32 * 33], wS11[32 * 33], wS12[32 * 33], wS21[32 * 33], wS22[32 * 33];
    __shared__ float mbl[32];
    const int tid = threadIdx.x;
    const int b = blockIdx.x >> 7, xn = blockIdx.x & 127;
    size_t base = (size_t)b * 524288 + xn * 128;
    for (int p = 0; p < 2; ++p) {
        int chunk = p * 256 + tid, c = chunk >> 4, l8 = (chunk & 15) * 8;
        size_t src = base + (size_t)c * 16384 + l8;
        *(uint4*)&Gs[c * 128 + l8]   = *(const uint4*)(G + src);
        *(uint4*)&H1s[c * 128 + l8]  = *(const uint4*)(H1 + src);
        *(uint4*)&H2s[c * 128 + l8]  = *(const uint4*)(H2 + src);
        *(uint4*)&H1bs[c * 128 + l8] = *(const uint4*)(H1b + src);
        *(uint4*)&H2bs[c * 128 + l8] = *(const uint4*)(H2b + src);
    }
    for (int i = tid; i < 1024; i += 256) {
        int o = i >> 5, c = i & 31;
        int d = o * 33 + c;
        wSg[d]  = mw1[o * 96 + c] + mw2[o * 96 + c];
        wS11[d] = mw1[o * 96 + 32 + c];
        wS12[d] = mw1[o * 96 + 64 + c];
        wS21[d] = mw2[o * 96 + 32 + c];
        wS22[d] = mw2[o * 96 + 64 + c];
    }
    if (tid < 32) mbl[tid] = mb1[tid] + mb2[tid];
    __syncthreads();
    const int og = (tid & 7) * 4, l0 = (tid >> 3) * 4;
    float acc[4][4];
    #pragma unroll
    for (int oi = 0; oi < 4; ++oi) {
        float bv = mbl[og + oi];
        acc[oi][0] = bv; acc[oi][1] = bv; acc[oi][2] = bv; acc[oi][3] = bv;
    }
    for (int c = 0; c < 32; ++c) {
        uint2 ga = *(const uint2*)&Gs[c * 128 + l0];
        uint2 h1 = *(const uint2*)&H1s[c * 128 + l0];
        uint2 h2 = *(const uint2*)&H2s[c * 128 + l0];
        uint2 j1 = *(const uint2*)&H1bs[c * 128 + l0];
        uint2 j2 = *(const uint2*)&H2bs[c * 128 + l0];
        float gv[4], v1[4], v2[4], u1[4], u2[4];
        gv[0] = __uint_as_float(ga.x << 16); gv[1] = __uint_as_float(ga.x & 0xffff0000u);
        gv[2] = __uint_as_float(ga.y << 16); gv[3] = __uint_as_float(ga.y & 0xffff0000u);
        v1[0] = __uint_as_float(h1.x << 16); v1[1] = __uint_as_float(h1.x & 0xffff0000u);
        v1[2] = __uint_as_float(h1.y << 16); v1[3] = __uint_as_float(h1.y & 0xffff0000u);
        v2[0] = __uint_as_float(h2.x << 16); v2[1] = __uint_as_float(h2.x & 0xffff0000u);
        v2[2] = __uint_as_float(h2.y << 16); v2[3] = __uint_as_float(h2.y & 0xffff0000u);
        u1[0] = __uint_as_float(j1.x << 16); u1[1] = __uint_as_float(j1.x & 0xffff0000u);
        u1[2] = __uint_as_float(j1.y << 16); u1[3] = __uint_as_float(j1.y & 0xffff0000u);
        u2[0] = __uint_as_float(j2.x << 16); u2[1] = __uint_as_float(j2.x & 0xffff0000u);
        u2[2] = __uint_as_float(j2.y << 16); u2[3] = __uint_as_float(j2.y & 0xffff0000u);
        #pragma unroll
        for (int oi = 0; oi < 4; ++oi) {
            int d = (og + oi) * 33 + c;
            float a0 = wSg[d], a1 = wS11[d], a2 = wS12[d], a3 = wS21[d], a4 = wS22[d];
            #pragma unroll
            for (int li = 0; li < 4; ++li)
                acc[oi][li] += gv[li] * a0 + v1[li] * a1 + v2[li] * a2
                             + u1[li] * a3 + u2[li] * a4;
        }
    }
    float s = 0.f, ss = 0.f;
    #pragma unroll
    for (int oi = 0; oi < 4; ++oi) {
        size_t e = ((size_t)(b * 32 + og + oi) * 128 + xn) * 128 + l0;
        f32x4 xv = *(const f32x4*)(x + e);
        float y0 = acc[oi][0] + xv[0];
        float y1 = acc[oi][1] + xv[1];
        float y2 = acc[oi][2] + xv[2];
        float y3 = acc[oi][3] + xv[3];
        s  += y0 + y1 + y2 + y3;
        ss += y0 * y0 + y1 * y1 + y2 * y2 + y3 * y3;
        uint2 rr;
        rr.x = cvt2bf(y0, y1);
        rr.y = cvt2bf(y2, y3);
        *(uint2*)(Y + e) = rr;
    }
    #pragma unroll
    for (int o = 32; o > 0; o >>= 1) {
        s  += __shfl_down(s,  o, 64);
        ss += __shfl_down(ss, o, 64);
    }
    __shared__ float sred[8];
    int w = tid >> 6;
    if ((tid & 63) == 0) { sred[w * 2] = s; sred[w * 2 + 1] = ss; }
    __syncthreads();
    if (tid == 0) {
        partial[blockIdx.x * 2]     = sred[0] + sred[2] + sred[4] + sred[6];
        partial[blockIdx.x * 2 + 1] = sred[1] + sred[3] + sred[5] + sred[7];
    }
}

// ---------------------------------------------------------------- LayerNorm finalize (Y bf16)
__global__ __launch_bounds__(256)
void k_lnnorm(const u16* __restrict__ Y,
              const float* __restrict__ partial, const int* __restrict__ idxp,
              const float* __restrict__ lnw, const float* __restrict__ lnb,
              float* __restrict__ outx)
{
    const int tid = threadIdx.x;
    const int b = blockIdx.x >> 7, chunk = blockIdx.x & 127;
    float s = 0.f, ss = 0.f;
    if (tid < 128) {
        s  = partial[(b * 128 + tid) * 2];
        ss = partial[(b * 128 + tid) * 2 + 1];
    }
    #pragma unroll
    for (int o = 32; o > 0; o >>= 1) {
        s  += __shfl_down(s,  o, 64);
        ss += __shfl_down(ss, o, 64);
    }
    __shared__ float sred[4];
    __shared__ float mv[2];
    if ((tid & 63) == 0 && tid < 128) { sred[(tid >> 6) * 2] = s; sred[(tid >> 6) * 2 + 1] = ss; }
    __syncthreads();
    if (tid == 0) {
        float S = sred[0] + sred[2], SS = sred[1] + sred[3];
        float mean = S * (1.f / 524288.f);
        float var = SS * (1.f / 524288.f) - mean * mean;
        mv[0] = mean; mv[1] = rsqrtf(var + 1e-5f);
    }
    __syncthreads();
    const float mean = mv[0], rstd = mv[1];
    #pragma unroll
    for (int q = 0; q < 4; ++q) {
        int ib = chunk * 4096 + q * 1024 + tid * 4;
        size_t e = (size_t)b * 524288 + ib;
        uint2 yv2 = *(const uint2*)(Y + e);
        float y[4];
        y[0] = __uint_as_float(yv2.x << 16); y[1] = __uint_as_float(yv2.x & 0xffff0000u);
        y[2] = __uint_as_float(yv2.y << 16); y[3] = __uint_as_float(yv2.y & 0xffff0000u);
        int c = ib >> 14, xn = (ib >> 7) & 127, l = ib & 127;
        int ix = idxp[xn];
        size_t we = ((size_t)c * 128 + ix) * 128 + l;
        f32x4 wv = *(const f32x4*)(lnw + we);
        f32x4 bv = *(const f32x4*)(lnb + we);
        f32x4 r;
        #pragma unroll
        for (int j = 0; j < 4; ++j)
            r[j] = (y[j] - mean) * rstd * wv[j] + bv[j];
        *(f32x4*)(outx + e) = r;
    }
}

// ---------------------------------------------------------------- launcher
extern "C" void kernel_launch(void* const* d_in, const int* in_sizes, int n_in,
                              void* d_out, int out_size, void* d_ws, size_t ws_size,
                              hipStream_t stream)
{
    (void)in_sizes; (void)n_in; (void)out_size; (void)ws_size;
    const float* x      = (const float*)d_in[0];
    const float* xskip  = (const float*)d_in[1];
    const float* A      = (const float*)d_in[2];
    const int*   idxp   = (const int*)d_in[3];
    const float* fw2p = (const float*)d_in[4];  const float* fb2p = (const float*)d_in[5];
    const float* fw3p = (const float*)d_in[6];  const float* fb3p = (const float*)d_in[7];
    const float* fw6p = (const float*)d_in[8];  const float* fb6p = (const float*)d_in[9];
    const float* fw7p = (const float*)d_in[10]; const float* fb7p = (const float*)d_in[11];
    const float* gw2p = (const float*)d_in[12]; const float* gb2p = (const float*)d_in[13];
    const float* gw3p = (const float*)d_in[14]; const float* gb3p = (const float*)d_in[15];
    const float* gw6p = (const float*)d_in[16]; const float* gb6p = (const float*)d_in[17];
    const float* gw7p = (const float*)d_in[18]; const float* gb7p = (const float*)d_in[19];
    const float* sw   = (const float*)d_in[20]; const float* sb   = (const float*)d_in[21];
    const float* mp1_gw = (const float*)d_in[22]; const float* mp1_gb = (const float*)d_in[23];
    const float* mp1_mw = (const float*)d_in[24]; const float* mp1_mb = (const float*)d_in[25];
    const float* mp2_gw = (const float*)d_in[26]; const float* mp2_gb = (const float*)d_in[27];
    const float* mp2_mw = (const float*)d_in[28]; const float* mp2_mb = (const float*)d_in[29];
    const float* lnw = (const float*)d_in[30]; const float* lnb = (const float*)d_in[31];

    char* wsb = (char*)d_ws;
    float* out_x  = (float*)d_out;
    float* out_sk = out_x + 8388608;

    const size_t MB16 = 16777216, MB33 = 33554432;
    u16*   G    = (u16*)(wsb);
    u16*   H1   = (u16*)(wsb + MB16);
    u16*   H1b  = (u16*)(wsb + 2 * MB16);
    u16*   H2   = (u16*)(wsb + 3 * MB16);
    u16*   H2b  = (u16*)(wsb + 4 * MB16);
    u16*   Wb0  = (u16*)(wsb + 5 * MB16);
    u16*   Wb1  = (u16*)(wsb + 5 * MB16 + MB33);
    u16*   Yb   = (u16*)Wb0;                        // bf16 Y, reuse after hop-2 GEMM
    float* XW0a = (float*)(wsb + 5 * MB16 + 2 * MB33);
    float* XW0b = (float*)(wsb + 5 * MB16 + 2 * MB33 + 2097152);
    float* part = (float*)(wsb + 5 * MB16 + 2 * MB33 + 4194304);
    float* dd   = (float*)(wsb + 5 * MB16 + 2 * MB33 + 4194304 + 16384);

    // 1: incskip | wcvt hop1 | prep
    k_mega1<<<18433, 256, 0, stream>>>(x, fw2p, fw3p, fw6p, fw7p, fb2p, fb3p, fb6p, fb7p,
                                       gw2p, gw3p, gw6p, gw7p, gb2p, gb3p, gb6p, gb7p,
                                       sw, sb, xskip, G, out_sk,
                                       mp1_gw, mp2_gw, Wb0, Wb1, A, dd);
    // 2: GEMM hop1
    k_gemm2g<<<256, 512, 0, stream>>>(G, G, Wb0, Wb1, G, mp1_gb, mp2_gb,
                                      H1, H1b, XW0a, XW0b);
    // 3: gcnfix hop1 | wcvt hop2 (reuses Wb0/Wb1)
    k_mega2<<<17408, 256, 0, stream>>>(XW0a, XW0b, G, A, dd, mp1_gb, mp2_gb,
                                       H1, H1b, mp1_gw + MB16, mp2_gw + MB16, Wb0, Wb1);
    // 4: GEMM hop2
    k_gemm2g<<<256, 512, 0, stream>>>(H1, H1b, Wb0, Wb1, G, mp1_gb + 4096, mp2_gb + 4096,
                                      H2, H2b, XW0a, XW0b);
    // 5: gcnfix hop2
    k_gcnfix<<<1024, 256, 0, stream>>>(XW0a, XW0b, G, A, dd,
                                       mp1_gb + 4096, mp2_gb + 4096, H2, H2b);
    // 6: fused channel-mix + residual + LN partials
    k_mix2ln<<<2048, 256, 0, stream>>>(G, H1, H2, H1b, H2b, mp1_mw, mp1_mb,
                                       mp2_mw, mp2_mb, x, Yb, part);
    // 7: LN finalize
    k_lnnorm<<<2048, 256, 0, stream>>>(Yb, part, idxp, lnw, lnb, out_x);
}